// Round 2
// baseline (464.254 us; speedup 1.0000x reference)
//
#include <hip/hip_runtime.h>
#include <hip/hip_bf16.h>

typedef __attribute__((ext_vector_type(8))) short short8;
typedef __attribute__((ext_vector_type(4))) short short4v;
typedef __attribute__((ext_vector_type(4))) float f32x4;

__device__ __forceinline__ unsigned short f32_bf16(float f) {
  unsigned u = __float_as_uint(f);
  u += 0x7fffu + ((u >> 16) & 1u);  // round-to-nearest-even
  return (unsigned short)(u >> 16);
}

__device__ __forceinline__ short8 cvt8(float4 v0, float4 v1) {
  short8 f;
  f[0] = (short)f32_bf16(v0.x); f[1] = (short)f32_bf16(v0.y);
  f[2] = (short)f32_bf16(v0.z); f[3] = (short)f32_bf16(v0.w);
  f[4] = (short)f32_bf16(v1.x); f[5] = (short)f32_bf16(v1.y);
  f[6] = (short)f32_bf16(v1.z); f[7] = (short)f32_bf16(v1.w);
  return f;
}

// ---- pass 1: z (fp32) -> z_bf16 in workspace --------------------------------
__global__ __launch_bounds__(256) void cvt_bf16_kernel(const float* __restrict__ z,
                                                       unsigned short* __restrict__ zb,
                                                       int n) {
  int i = (blockIdx.x * 256 + threadIdx.x) * 8;
  if (i + 8 <= n) {
    float4 v0 = *(const float4*)(z + i);
    float4 v1 = *(const float4*)(z + i + 4);
    union { unsigned short us[8]; uint4 u4; } r;
    r.us[0] = f32_bf16(v0.x); r.us[1] = f32_bf16(v0.y);
    r.us[2] = f32_bf16(v0.z); r.us[3] = f32_bf16(v0.w);
    r.us[4] = f32_bf16(v1.x); r.us[5] = f32_bf16(v1.y);
    r.us[6] = f32_bf16(v1.z); r.us[7] = f32_bf16(v1.w);
    *(uint4*)(zb + i) = r.u4;
  }
}

// ---- pass 2: fused gather + 3-layer MLP + sigmoid ---------------------------
// 512-thread blocks (8 waves), 2 blocks/CU. Each wave: 32 edges/iter (two
// 16-edge MFMA m-tiles sharing W fragments read from LDS).
// A-frag: a[j]=A[m=lane&15][k=quad*8+j]; B-frag: b[j]=B[k=quad*8+j][n=lane&15]
// C/D:    D[row=quad*4+reg][col=lane&15]
// W1 fragments stored column-PERMUTED: ntile t, lane l15 holds col l15*4+t,
// so each lane's 4 outputs (t=0..3) are contiguous h1 cols -> one ds_write_b64.
#define STRH1 80  // h1 row stride in shorts (160B: 16B-aligned rows, mild 4-way read conflicts)

template <bool ZBF>
__global__ __launch_bounds__(512, 4) void lp_main(
    const float* __restrict__ zf, const unsigned short* __restrict__ zb,
    const int* __restrict__ ei,
    const float* __restrict__ W1, const float* __restrict__ b1,
    const float* __restrict__ W2, const float* __restrict__ b2,
    const float* __restrict__ W3, const float* __restrict__ b3,
    float* __restrict__ out, int nEdges) {
  __shared__ unsigned short w1l[32 * 64 * 8];   // 32 KB: (c*4+t, lane) -> 8 bf16
  __shared__ unsigned short w2l[4 * 64 * 8];    // 4 KB:  (c*2+t, lane) -> 8 bf16
  __shared__ unsigned short h1s[8 * 16 * STRH1];// 20 KB: per-wave [16][80]

  const int tid = threadIdx.x;
  const int wv  = tid >> 6;
  const int l   = tid & 63;
  const int l15 = l & 15;
  const int q   = l >> 4;

  // ---- stage W1 fragments into LDS (once per block, col-permuted) ----
#pragma unroll
  for (int pp = 0; pp < 4; ++pp) {
    int p = wv * 4 + pp;  // p = c*4 + t
    int c = p >> 2, t = p & 3;
    short8 f;
#pragma unroll
    for (int j = 0; j < 8; ++j)
      f[j] = (short)f32_bf16(W1[(c * 32 + q * 8 + j) * 64 + (l15 * 4 + t)]);
    *(short8*)(w1l + (p * 64 + l) * 8) = f;
  }
  // ---- stage W2 fragments (natural column order) ----
  if (tid < 256) {
    int p = tid >> 6;  // p = c*2 + t
    int c = p >> 1, t = p & 1;
    int ll = tid & 63, lb = ll & 15, qb = ll >> 4;
    short8 f;
#pragma unroll
    for (int j = 0; j < 8; ++j)
      f[j] = (short)f32_bf16(W2[(c * 32 + qb * 8 + j) * 32 + (t * 16 + lb)]);
    *(short8*)(w2l + (p * 64 + ll) * 8) = f;
  }

  float bb1[4];
#pragma unroll
  for (int t = 0; t < 4; ++t) bb1[t] = b1[l15 * 4 + t];  // permuted cols
  float bb2[2];
#pragma unroll
  for (int t = 0; t < 2; ++t) bb2[t] = b2[t * 16 + l15];
  const float w3a = W3[l15], w3b = W3[16 + l15], b3v = b3[0];

  __syncthreads();

  unsigned short* h1p = h1s + wv * (16 * STRH1);

  const int nIter = (nEdges + 31) >> 5;
  const int stride = gridDim.x * 8;
  int iter = blockIdx.x * 8 + wv;

  // prefetch edge indices for first iteration
  int cS0 = 0, cD0 = 0, cS1 = 0, cD1 = 0;
  if (iter < nIter) {
    int base = iter * 32;
    int e0 = base + l15;      e0 = e0 < nEdges ? e0 : nEdges - 1;
    int e1 = base + 16 + l15; e1 = e1 < nEdges ? e1 : nEdges - 1;
    cS0 = ei[e0]; cD0 = ei[nEdges + e0];
    cS1 = ei[e1]; cD1 = ei[nEdges + e1];
  }

  for (; iter < nIter; iter += stride) {
    // ---- gather both 16-edge tiles (loads issue up front) ----
    short8 a0[8], a1[8];
    if (ZBF) {
      const unsigned short* r0 = zb + (size_t)cS0 * 128;
      const unsigned short* r1 = zb + (size_t)cD0 * 128;
      const unsigned short* r2 = zb + (size_t)cS1 * 128;
      const unsigned short* r3 = zb + (size_t)cD1 * 128;
#pragma unroll
      for (int c = 0; c < 4; ++c) {
        int off = c * 32 + q * 8;
        a0[c] = *(const short8*)(r0 + off); a0[c + 4] = *(const short8*)(r1 + off);
        a1[c] = *(const short8*)(r2 + off); a1[c + 4] = *(const short8*)(r3 + off);
      }
    } else {
      const float* r0 = zf + (size_t)cS0 * 128;
      const float* r1 = zf + (size_t)cD0 * 128;
      const float* r2 = zf + (size_t)cS1 * 128;
      const float* r3 = zf + (size_t)cD1 * 128;
#pragma unroll
      for (int c = 0; c < 4; ++c) {
        int off = c * 32 + q * 8;
        a0[c]     = cvt8(*(const float4*)(r0 + off), *(const float4*)(r0 + off + 4));
        a0[c + 4] = cvt8(*(const float4*)(r1 + off), *(const float4*)(r1 + off + 4));
        a1[c]     = cvt8(*(const float4*)(r2 + off), *(const float4*)(r2 + off + 4));
        a1[c + 4] = cvt8(*(const float4*)(r3 + off), *(const float4*)(r3 + off + 4));
      }
    }

    // ---- prefetch edge indices for next iteration ----
    int nit = iter + stride;
    int nS0 = cS0, nD0 = cD0, nS1 = cS1, nD1 = cD1;
    if (nit < nIter) {
      int base = nit * 32;
      int e0 = base + l15;      e0 = e0 < nEdges ? e0 : nEdges - 1;
      int e1 = base + 16 + l15; e1 = e1 < nEdges ? e1 : nEdges - 1;
      nS0 = ei[e0]; nD0 = ei[nEdges + e0];
      nS1 = ei[e1]; nD1 = ei[nEdges + e1];
    }

    // ---- layer 1: two m-tiles share each W1 fragment ----
    f32x4 acc0[4], acc1[4];
#pragma unroll
    for (int t = 0; t < 4; ++t) {
      acc0[t][0] = bb1[t]; acc0[t][1] = bb1[t]; acc0[t][2] = bb1[t]; acc0[t][3] = bb1[t];
      acc1[t][0] = bb1[t]; acc1[t][1] = bb1[t]; acc1[t][2] = bb1[t]; acc1[t][3] = bb1[t];
    }
#pragma unroll
    for (int c = 0; c < 8; ++c)
#pragma unroll
      for (int t = 0; t < 4; ++t) {
        short8 wf = *(const short8*)(w1l + ((c * 4 + t) * 64 + l) * 8);
        acc0[t] = __builtin_amdgcn_mfma_f32_16x16x32_bf16(a0[c], wf, acc0[t], 0, 0, 0);
        acc1[t] = __builtin_amdgcn_mfma_f32_16x16x32_bf16(a1[c], wf, acc1[t], 0, 0, 0);
      }

    // ---- per tile-half: relu -> h1 -> layer2 -> shuffle layer3 -> store ----
#pragma unroll
    for (int h = 0; h < 2; ++h) {
      f32x4* acc = h ? acc1 : acc0;
      // relu + cvt + vectorized h1 write (4x ds_write_b64)
#pragma unroll
      for (int r = 0; r < 4; ++r) {
        short4v v;
#pragma unroll
        for (int t = 0; t < 4; ++t) {
          float x = acc[t][r];
          x = x > 0.f ? x : 0.f;
          v[t] = (short)f32_bf16(x);
        }
        *(short4v*)(h1p + (q * 4 + r) * STRH1 + l15 * 4) = v;
      }

      // layer 2: [16,64] @ [64,32]
      short8 a2_0 = *(const short8*)(h1p + l15 * STRH1 + q * 8);
      short8 a2_1 = *(const short8*)(h1p + l15 * STRH1 + 32 + q * 8);
      f32x4 acc2[2];
#pragma unroll
      for (int t = 0; t < 2; ++t) {
        acc2[t][0] = bb2[t]; acc2[t][1] = bb2[t]; acc2[t][2] = bb2[t]; acc2[t][3] = bb2[t];
      }
#pragma unroll
      for (int t = 0; t < 2; ++t) {
        short8 wf0 = *(const short8*)(w2l + ((0 * 2 + t) * 64 + l) * 8);
        acc2[t] = __builtin_amdgcn_mfma_f32_16x16x32_bf16(a2_0, wf0, acc2[t], 0, 0, 0);
        short8 wf1 = *(const short8*)(w2l + ((1 * 2 + t) * 64 + l) * 8);
        acc2[t] = __builtin_amdgcn_mfma_f32_16x16x32_bf16(a2_1, wf1, acc2[t], 0, 0, 0);
      }

      // layer 3: per-lane partial, then xor-reduce across the 16 lanes of each quad
      float p[4];
#pragma unroll
      for (int r = 0; r < 4; ++r) {
        float h0 = acc2[0][r]; h0 = h0 > 0.f ? h0 : 0.f;
        float h1v = acc2[1][r]; h1v = h1v > 0.f ? h1v : 0.f;
        p[r] = h0 * w3a + h1v * w3b;
      }
#pragma unroll
      for (int m = 1; m < 16; m <<= 1)
#pragma unroll
        for (int r = 0; r < 4; ++r) p[r] += __shfl_xor(p[r], m, 64);

      if (l15 == 0) {
        int eb = iter * 32 + h * 16 + q * 4;
        float4 o;
        o.x = 1.f / (1.f + __expf(-(p[0] + b3v)));
        o.y = 1.f / (1.f + __expf(-(p[1] + b3v)));
        o.z = 1.f / (1.f + __expf(-(p[2] + b3v)));
        o.w = 1.f / (1.f + __expf(-(p[3] + b3v)));
        if (eb + 3 < nEdges) {
          *(float4*)(out + eb) = o;
        } else {
          if (eb < nEdges)     out[eb]     = o.x;
          if (eb + 1 < nEdges) out[eb + 1] = o.y;
          if (eb + 2 < nEdges) out[eb + 2] = o.z;
        }
      }
    }

    cS0 = nS0; cD0 = nD0; cS1 = nS1; cD1 = nD1;
  }
}

extern "C" void kernel_launch(void* const* d_in, const int* in_sizes, int n_in,
                              void* d_out, int out_size, void* d_ws, size_t ws_size,
                              hipStream_t stream) {
  const float* z  = (const float*)d_in[0];
  const int* ei   = (const int*)d_in[1];
  const float* W1 = (const float*)d_in[2];
  const float* b1 = (const float*)d_in[3];
  const float* W2 = (const float*)d_in[4];
  const float* b2 = (const float*)d_in[5];
  const float* W3 = (const float*)d_in[6];
  const float* b3 = (const float*)d_in[7];
  float* out = (float*)d_out;

  const int nZ = in_sizes[0];
  const int nEdges = in_sizes[1] / 2;

  const bool useWs = ws_size >= (size_t)nZ * sizeof(unsigned short);
  if (useWs) {
    unsigned short* zb = (unsigned short*)d_ws;
    int nThr = nZ / 8;
    cvt_bf16_kernel<<<(nThr + 255) / 256, 256, 0, stream>>>(z, zb, nZ);
    lp_main<true><<<512, 512, 0, stream>>>(z, zb, ei, W1, b1, W2, b2, W3, b3, out, nEdges);
  } else {
    lp_main<false><<<512, 512, 0, stream>>>(z, nullptr, ei, W1, b1, W2, b2, W3, b3, out, nEdges);
  }
}

// Round 3
// 432.167 us; speedup vs baseline: 1.0742x; 1.0742x over previous
//
#include <hip/hip_runtime.h>
#include <hip/hip_bf16.h>

typedef __attribute__((ext_vector_type(8))) short short8;
typedef __attribute__((ext_vector_type(4))) short short4v;
typedef __attribute__((ext_vector_type(4))) float f32x4;

__device__ __forceinline__ unsigned short f32_bf16(float f) {
  unsigned u = __float_as_uint(f);
  u += 0x7fffu + ((u >> 16) & 1u);  // round-to-nearest-even
  return (unsigned short)(u >> 16);
}

__device__ __forceinline__ short8 cvt8(float4 v0, float4 v1) {
  short8 f;
  f[0] = (short)f32_bf16(v0.x); f[1] = (short)f32_bf16(v0.y);
  f[2] = (short)f32_bf16(v0.z); f[3] = (short)f32_bf16(v0.w);
  f[4] = (short)f32_bf16(v1.x); f[5] = (short)f32_bf16(v1.y);
  f[6] = (short)f32_bf16(v1.z); f[7] = (short)f32_bf16(v1.w);
  return f;
}

// ---- pass 1: z (fp32) -> z_bf16 in workspace --------------------------------
__global__ __launch_bounds__(256) void cvt_bf16_kernel(const float* __restrict__ z,
                                                       unsigned short* __restrict__ zb,
                                                       int n) {
  int i = (blockIdx.x * 256 + threadIdx.x) * 8;
  if (i + 8 <= n) {
    float4 v0 = *(const float4*)(z + i);
    float4 v1 = *(const float4*)(z + i + 4);
    union { unsigned short us[8]; uint4 u4; } r;
    r.us[0] = f32_bf16(v0.x); r.us[1] = f32_bf16(v0.y);
    r.us[2] = f32_bf16(v0.z); r.us[3] = f32_bf16(v0.w);
    r.us[4] = f32_bf16(v1.x); r.us[5] = f32_bf16(v1.y);
    r.us[6] = f32_bf16(v1.z); r.us[7] = f32_bf16(v1.w);
    *(uint4*)(zb + i) = r.u4;
  }
}

// ---- pass 2: fused gather + 3-layer MLP + sigmoid ---------------------------
// 256-thread blocks (4 waves), (256,4) launch bounds -> 128-reg cap, no spill
// for the 1-m-tile structure (~95 regs). LDS/block = 32KB (W1 frags) + 8KB
// (per-wave h1 scratch, XOR-swizzled) = 40960 B -> exactly 4 blocks/CU,
// 16 waves/CU target occupancy.
// A-frag: a[j]=A[m=lane&15][k=quad*8+j]; B-frag: b[j]=B[k=quad*8+j][n=lane&15]
// C/D:    D[row=quad*4+reg][col=lane&15]
// W1 fragments stored column-PERMUTED (ntile t, lane l15 -> col l15*4+t) so a
// lane's 4 layer-1 outputs are contiguous h1 cols -> one ds_write_b64.
// h1 swizzle: col' = (col + (row&7)*8) & 63  (keeps 4/8-element runs intact).
template <bool ZBF>
__global__ __launch_bounds__(256, 4) void lp_main(
    const float* __restrict__ zf, const unsigned short* __restrict__ zb,
    const int* __restrict__ ei,
    const float* __restrict__ W1, const float* __restrict__ b1,
    const float* __restrict__ W2, const float* __restrict__ b2,
    const float* __restrict__ W3, const float* __restrict__ b3,
    float* __restrict__ out, int nEdges) {
  __shared__ unsigned short w1l[32 * 64 * 8];            // 32 KB
  __shared__ __align__(16) unsigned short h1s[4][16 * 64];  // 8 KB

  const int tid = threadIdx.x;
  const int wv  = tid >> 6;
  const int l   = tid & 63;
  const int l15 = l & 15;
  const int q   = l >> 4;

  // ---- stage W1 fragments into LDS (once per block, col-permuted) ----
#pragma unroll
  for (int pp = 0; pp < 8; ++pp) {
    int p = wv * 8 + pp;  // p = c*4 + t
    int c = p >> 2, t = p & 3;
    short8 f;
#pragma unroll
    for (int j = 0; j < 8; ++j)
      f[j] = (short)f32_bf16(W1[(c * 32 + q * 8 + j) * 64 + (l15 * 4 + t)]);
    *(short8*)(w1l + (p * 64 + l) * 8) = f;
  }

  // ---- W2 fragments in registers (natural column order) ----
  short8 w2f[2][2];
#pragma unroll
  for (int c = 0; c < 2; ++c)
#pragma unroll
    for (int t = 0; t < 2; ++t) {
      short8 f;
#pragma unroll
      for (int j = 0; j < 8; ++j)
        f[j] = (short)f32_bf16(W2[(c * 32 + q * 8 + j) * 32 + (t * 16 + l15)]);
      w2f[c][t] = f;
    }

  float bb1[4];
#pragma unroll
  for (int t = 0; t < 4; ++t) bb1[t] = b1[l15 * 4 + t];  // permuted cols
  float bb2[2];
#pragma unroll
  for (int t = 0; t < 2; ++t) bb2[t] = b2[t * 16 + l15];
  const float w3a = W3[l15], w3b = W3[16 + l15], b3v = b3[0];

  __syncthreads();

  unsigned short* h1p = h1s[wv];

  const int nIter = (nEdges + 15) >> 4;
  const int stride = gridDim.x * 4;
  int iter = blockIdx.x * 4 + wv;

  // prefetch edge indices for first iteration
  int cS = 0, cD = 0;
  if (iter < nIter) {
    int e = iter * 16 + l15;
    e = e < nEdges ? e : nEdges - 1;
    cS = ei[e];
    cD = ei[nEdges + e];
  }

  for (; iter < nIter; iter += stride) {
    // ---- gather this tile's A fragments ----
    short8 a[8];
    if (ZBF) {
      const unsigned short* rs = zb + (size_t)cS * 128;
      const unsigned short* rd = zb + (size_t)cD * 128;
#pragma unroll
      for (int c = 0; c < 4; ++c) {
        int off = c * 32 + q * 8;
        a[c]     = *(const short8*)(rs + off);
        a[c + 4] = *(const short8*)(rd + off);
      }
    } else {
      const float* rs = zf + (size_t)cS * 128;
      const float* rd = zf + (size_t)cD * 128;
#pragma unroll
      for (int c = 0; c < 4; ++c) {
        int off = c * 32 + q * 8;
        a[c]     = cvt8(*(const float4*)(rs + off), *(const float4*)(rs + off + 4));
        a[c + 4] = cvt8(*(const float4*)(rd + off), *(const float4*)(rd + off + 4));
      }
    }

    // ---- prefetch edge indices for next iteration ----
    int nit = iter + stride;
    int nS = cS, nD = cD;
    if (nit < nIter) {
      int e = nit * 16 + l15;
      e = e < nEdges ? e : nEdges - 1;
      nS = ei[e];
      nD = ei[nEdges + e];
    }

    // ---- layer 1: [16,256] @ [256,64] + b1, W1 frags from LDS ----
    f32x4 acc[4];
#pragma unroll
    for (int t = 0; t < 4; ++t) {
      acc[t][0] = bb1[t]; acc[t][1] = bb1[t]; acc[t][2] = bb1[t]; acc[t][3] = bb1[t];
    }
#pragma unroll
    for (int c = 0; c < 8; ++c)
#pragma unroll
      for (int t = 0; t < 4; ++t) {
        short8 wf = *(const short8*)(w1l + ((c * 4 + t) * 64 + l) * 8);
        acc[t] = __builtin_amdgcn_mfma_f32_16x16x32_bf16(a[c], wf, acc[t], 0, 0, 0);
      }

    // ---- relu -> bf16 -> swizzled h1 (one ds_write_b64 per row) ----
#pragma unroll
    for (int r = 0; r < 4; ++r) {
      int m = q * 4 + r;
      int colb = (l15 * 4 + ((m & 7) << 3)) & 63;
      short4v v;
#pragma unroll
      for (int t = 0; t < 4; ++t) {
        float x = acc[t][r];
        x = x > 0.f ? x : 0.f;
        v[t] = (short)f32_bf16(x);
      }
      *(short4v*)(h1p + m * 64 + colb) = v;
    }

    // ---- layer 2: [16,64] @ [64,32] + b2 (per-wave LDS, no barrier) ----
    int rot = (l15 & 7) << 3;
    short8 a2_0 = *(const short8*)(h1p + l15 * 64 + ((q * 8 + rot) & 63));
    short8 a2_1 = *(const short8*)(h1p + l15 * 64 + ((q * 8 + 32 + rot) & 63));

    f32x4 acc2[2];
#pragma unroll
    for (int t = 0; t < 2; ++t) {
      acc2[t][0] = bb2[t]; acc2[t][1] = bb2[t]; acc2[t][2] = bb2[t]; acc2[t][3] = bb2[t];
    }
#pragma unroll
    for (int t = 0; t < 2; ++t) {
      acc2[t] = __builtin_amdgcn_mfma_f32_16x16x32_bf16(a2_0, w2f[0][t], acc2[t], 0, 0, 0);
      acc2[t] = __builtin_amdgcn_mfma_f32_16x16x32_bf16(a2_1, w2f[1][t], acc2[t], 0, 0, 0);
    }

    // ---- layer 3: per-lane partial, xor-reduce across 16 lanes ----
    float p[4];
#pragma unroll
    for (int r = 0; r < 4; ++r) {
      float h0 = acc2[0][r]; h0 = h0 > 0.f ? h0 : 0.f;
      float h1v = acc2[1][r]; h1v = h1v > 0.f ? h1v : 0.f;
      p[r] = h0 * w3a + h1v * w3b;
    }
#pragma unroll
    for (int m = 1; m < 16; m <<= 1)
#pragma unroll
      for (int r = 0; r < 4; ++r) p[r] += __shfl_xor(p[r], m, 64);

    if (l15 == 0) {
      int eb = iter * 16 + q * 4;
      float4 o;
      o.x = 1.f / (1.f + __expf(-(p[0] + b3v)));
      o.y = 1.f / (1.f + __expf(-(p[1] + b3v)));
      o.z = 1.f / (1.f + __expf(-(p[2] + b3v)));
      o.w = 1.f / (1.f + __expf(-(p[3] + b3v)));
      if (eb + 3 < nEdges) {
        *(float4*)(out + eb) = o;
      } else {
        if (eb < nEdges)     out[eb]     = o.x;
        if (eb + 1 < nEdges) out[eb + 1] = o.y;
        if (eb + 2 < nEdges) out[eb + 2] = o.z;
      }
    }

    cS = nS; cD = nD;
  }
}

extern "C" void kernel_launch(void* const* d_in, const int* in_sizes, int n_in,
                              void* d_out, int out_size, void* d_ws, size_t ws_size,
                              hipStream_t stream) {
  const float* z  = (const float*)d_in[0];
  const int* ei   = (const int*)d_in[1];
  const float* W1 = (const float*)d_in[2];
  const float* b1 = (const float*)d_in[3];
  const float* W2 = (const float*)d_in[4];
  const float* b2 = (const float*)d_in[5];
  const float* W3 = (const float*)d_in[6];
  const float* b3 = (const float*)d_in[7];
  float* out = (float*)d_out;

  const int nZ = in_sizes[0];
  const int nEdges = in_sizes[1] / 2;

  const bool useWs = ws_size >= (size_t)nZ * sizeof(unsigned short);
  if (useWs) {
    unsigned short* zb = (unsigned short*)d_ws;
    int nThr = nZ / 8;
    cvt_bf16_kernel<<<(nThr + 255) / 256, 256, 0, stream>>>(z, zb, nZ);
    lp_main<true><<<1024, 256, 0, stream>>>(z, zb, ei, W1, b1, W2, b2, W3, b3, out, nEdges);
  } else {
    lp_main<false><<<1024, 256, 0, stream>>>(z, nullptr, ei, W1, b1, W2, b2, W3, b3, out, nEdges);
  }
}

// Round 4
// 416.293 us; speedup vs baseline: 1.1152x; 1.0381x over previous
//
#include <hip/hip_runtime.h>
#include <hip/hip_bf16.h>

typedef __attribute__((ext_vector_type(8))) short short8;
typedef __attribute__((ext_vector_type(4))) short short4v;
typedef __attribute__((ext_vector_type(4))) float f32x4;

__device__ __forceinline__ unsigned short f32_bf16(float f) {
  unsigned u = __float_as_uint(f);
  u += 0x7fffu + ((u >> 16) & 1u);  // round-to-nearest-even
  return (unsigned short)(u >> 16);
}

__device__ __forceinline__ short8 cvt8(float4 v0, float4 v1) {
  short8 f;
  f[0] = (short)f32_bf16(v0.x); f[1] = (short)f32_bf16(v0.y);
  f[2] = (short)f32_bf16(v0.z); f[3] = (short)f32_bf16(v0.w);
  f[4] = (short)f32_bf16(v1.x); f[5] = (short)f32_bf16(v1.y);
  f[6] = (short)f32_bf16(v1.z); f[7] = (short)f32_bf16(v1.w);
  return f;
}

// ---- pass 1: z (fp32) -> z_bf16 in workspace --------------------------------
__global__ __launch_bounds__(256) void cvt_bf16_kernel(const float* __restrict__ z,
                                                       unsigned short* __restrict__ zb,
                                                       int n) {
  int i = (blockIdx.x * 256 + threadIdx.x) * 8;
  if (i + 8 <= n) {
    float4 v0 = *(const float4*)(z + i);
    float4 v1 = *(const float4*)(z + i + 4);
    union { unsigned short us[8]; uint4 u4; } r;
    r.us[0] = f32_bf16(v0.x); r.us[1] = f32_bf16(v0.y);
    r.us[2] = f32_bf16(v0.z); r.us[3] = f32_bf16(v0.w);
    r.us[4] = f32_bf16(v1.x); r.us[5] = f32_bf16(v1.y);
    r.us[6] = f32_bf16(v1.z); r.us[7] = f32_bf16(v1.w);
    *(uint4*)(zb + i) = r.u4;
  }
}

// ---- pass 2: fused gather + 3-layer MLP + sigmoid ---------------------------
// 256-thread blocks (4 waves). __launch_bounds__(256,3) -> ~170-reg cap; the
// kernel needs ~110 total (arch+acc), so NO SPILL (R2/R3 died on the forced
// 64-arch-VGPR split under a 128 cap: 117-318 MB of scratch traffic).
// LDS/block = 32KB (W1 frags) + 8KB (per-wave h1 scratch) = 40960 B -> 4
// blocks/CU by LDS; registers decide 3-4 waves/SIMD.
// A-frag: a[j]=A[m=lane&15][k=quad*8+j]; B-frag: b[j]=B[k=quad*8+j][n=lane&15]
// C/D:    D[row=quad*4+reg][col=lane&15]
// W1 fragments stored column-PERMUTED (ntile t, lane l15 -> col l15*4+t) so a
// lane's 4 layer-1 outputs are contiguous h1 cols -> one ds_write_b64.
// h1 swizzle: col' = (col + (row&7)*8) & 63  (keeps 4/8-element runs intact).
template <bool ZBF>
__global__ __launch_bounds__(256, 3) void lp_main(
    const float* __restrict__ zf, const unsigned short* __restrict__ zb,
    const int* __restrict__ ei,
    const float* __restrict__ W1, const float* __restrict__ b1,
    const float* __restrict__ W2, const float* __restrict__ b2,
    const float* __restrict__ W3, const float* __restrict__ b3,
    float* __restrict__ out, int nEdges) {
  __shared__ unsigned short w1l[32 * 64 * 8];               // 32 KB
  __shared__ __align__(16) unsigned short h1s[4][16 * 64];  // 8 KB

  const int tid = threadIdx.x;
  const int wv  = tid >> 6;
  const int l   = tid & 63;
  const int l15 = l & 15;
  const int q   = l >> 4;

  // ---- stage W1 fragments into LDS (once per block, col-permuted) ----
#pragma unroll
  for (int pp = 0; pp < 8; ++pp) {
    int p = wv * 8 + pp;  // p = c*4 + t
    int c = p >> 2, t = p & 3;
    short8 f;
#pragma unroll
    for (int j = 0; j < 8; ++j)
      f[j] = (short)f32_bf16(W1[(c * 32 + q * 8 + j) * 64 + (l15 * 4 + t)]);
    *(short8*)(w1l + (p * 64 + l) * 8) = f;
  }

  // ---- W2 fragments in registers (natural column order) ----
  short8 w2f[2][2];
#pragma unroll
  for (int c = 0; c < 2; ++c)
#pragma unroll
    for (int t = 0; t < 2; ++t) {
      short8 f;
#pragma unroll
      for (int j = 0; j < 8; ++j)
        f[j] = (short)f32_bf16(W2[(c * 32 + q * 8 + j) * 32 + (t * 16 + l15)]);
      w2f[c][t] = f;
    }

  float bb1[4];
#pragma unroll
  for (int t = 0; t < 4; ++t) bb1[t] = b1[l15 * 4 + t];  // permuted cols
  float bb2[2];
#pragma unroll
  for (int t = 0; t < 2; ++t) bb2[t] = b2[t * 16 + l15];
  const float w3a = W3[l15], w3b = W3[16 + l15], b3v = b3[0];

  __syncthreads();

  unsigned short* h1p = h1s[wv];

  const int nIter = (nEdges + 15) >> 4;
  const int stride = gridDim.x * 4;
  int iter = blockIdx.x * 4 + wv;

  // prefetch edge indices for first iteration
  int cS = 0, cD = 0;
  if (iter < nIter) {
    int e = iter * 16 + l15;
    e = e < nEdges ? e : nEdges - 1;
    cS = ei[e];
    cD = ei[nEdges + e];
  }

  for (; iter < nIter; iter += stride) {
    // ---- gather this tile's A fragments ----
    short8 a[8];
    if (ZBF) {
      const unsigned short* rs = zb + (size_t)cS * 128;
      const unsigned short* rd = zb + (size_t)cD * 128;
#pragma unroll
      for (int c = 0; c < 4; ++c) {
        int off = c * 32 + q * 8;
        a[c]     = *(const short8*)(rs + off);
        a[c + 4] = *(const short8*)(rd + off);
      }
    } else {
      const float* rs = zf + (size_t)cS * 128;
      const float* rd = zf + (size_t)cD * 128;
#pragma unroll
      for (int c = 0; c < 4; ++c) {
        int off = c * 32 + q * 8;
        a[c]     = cvt8(*(const float4*)(rs + off), *(const float4*)(rs + off + 4));
        a[c + 4] = cvt8(*(const float4*)(rd + off), *(const float4*)(rd + off + 4));
      }
    }

    // ---- prefetch edge indices for next iteration ----
    int nit = iter + stride;
    int nS = cS, nD = cD;
    if (nit < nIter) {
      int e = nit * 16 + l15;
      e = e < nEdges ? e : nEdges - 1;
      nS = ei[e];
      nD = ei[nEdges + e];
    }

    // ---- layer 1: [16,256] @ [256,64] + b1, W1 frags from LDS ----
    f32x4 acc[4];
#pragma unroll
    for (int t = 0; t < 4; ++t) {
      acc[t][0] = bb1[t]; acc[t][1] = bb1[t]; acc[t][2] = bb1[t]; acc[t][3] = bb1[t];
    }
#pragma unroll
    for (int c = 0; c < 8; ++c)
#pragma unroll
      for (int t = 0; t < 4; ++t) {
        short8 wf = *(const short8*)(w1l + ((c * 4 + t) * 64 + l) * 8);
        acc[t] = __builtin_amdgcn_mfma_f32_16x16x32_bf16(a[c], wf, acc[t], 0, 0, 0);
      }

    // ---- relu -> bf16 -> swizzled h1 (one ds_write_b64 per row) ----
#pragma unroll
    for (int r = 0; r < 4; ++r) {
      int m = q * 4 + r;
      int colb = (l15 * 4 + ((m & 7) << 3)) & 63;
      short4v v;
#pragma unroll
      for (int t = 0; t < 4; ++t) {
        float x = acc[t][r];
        x = x > 0.f ? x : 0.f;
        v[t] = (short)f32_bf16(x);
      }
      *(short4v*)(h1p + m * 64 + colb) = v;
    }

    // ---- layer 2: [16,64] @ [64,32] + b2 (per-wave LDS, no barrier) ----
    int rot = (l15 & 7) << 3;
    short8 a2_0 = *(const short8*)(h1p + l15 * 64 + ((q * 8 + rot) & 63));
    short8 a2_1 = *(const short8*)(h1p + l15 * 64 + ((q * 8 + 32 + rot) & 63));

    f32x4 acc2[2];
#pragma unroll
    for (int t = 0; t < 2; ++t) {
      acc2[t][0] = bb2[t]; acc2[t][1] = bb2[t]; acc2[t][2] = bb2[t]; acc2[t][3] = bb2[t];
    }
#pragma unroll
    for (int t = 0; t < 2; ++t) {
      acc2[t] = __builtin_amdgcn_mfma_f32_16x16x32_bf16(a2_0, w2f[0][t], acc2[t], 0, 0, 0);
      acc2[t] = __builtin_amdgcn_mfma_f32_16x16x32_bf16(a2_1, w2f[1][t], acc2[t], 0, 0, 0);
    }

    // ---- layer 3: per-lane partial, xor-reduce across 16 lanes ----
    float p[4];
#pragma unroll
    for (int r = 0; r < 4; ++r) {
      float h0 = acc2[0][r]; h0 = h0 > 0.f ? h0 : 0.f;
      float h1v = acc2[1][r]; h1v = h1v > 0.f ? h1v : 0.f;
      p[r] = h0 * w3a + h1v * w3b;
    }
#pragma unroll
    for (int m = 1; m < 16; m <<= 1)
#pragma unroll
      for (int r = 0; r < 4; ++r) p[r] += __shfl_xor(p[r], m, 64);

    if (l15 == 0) {
      int eb = iter * 16 + q * 4;
      float4 o;
      o.x = 1.f / (1.f + __expf(-(p[0] + b3v)));
      o.y = 1.f / (1.f + __expf(-(p[1] + b3v)));
      o.z = 1.f / (1.f + __expf(-(p[2] + b3v)));
      o.w = 1.f / (1.f + __expf(-(p[3] + b3v)));
      if (eb + 3 < nEdges) {
        *(float4*)(out + eb) = o;
      } else {
        if (eb < nEdges)     out[eb]     = o.x;
        if (eb + 1 < nEdges) out[eb + 1] = o.y;
        if (eb + 2 < nEdges) out[eb + 2] = o.z;
      }
    }

    cS = nS; cD = nD;
  }
}

extern "C" void kernel_launch(void* const* d_in, const int* in_sizes, int n_in,
                              void* d_out, int out_size, void* d_ws, size_t ws_size,
                              hipStream_t stream) {
  const float* z  = (const float*)d_in[0];
  const int* ei   = (const int*)d_in[1];
  const float* W1 = (const float*)d_in[2];
  const float* b1 = (const float*)d_in[3];
  const float* W2 = (const float*)d_in[4];
  const float* b2 = (const float*)d_in[5];
  const float* W3 = (const float*)d_in[6];
  const float* b3 = (const float*)d_in[7];
  float* out = (float*)d_out;

  const int nZ = in_sizes[0];
  const int nEdges = in_sizes[1] / 2;

  const bool useWs = ws_size >= (size_t)nZ * sizeof(unsigned short);
  if (useWs) {
    unsigned short* zb = (unsigned short*)d_ws;
    int nThr = nZ / 8;
    cvt_bf16_kernel<<<(nThr + 255) / 256, 256, 0, stream>>>(z, zb, nZ);
    lp_main<true><<<1024, 256, 0, stream>>>(z, zb, ei, W1, b1, W2, b2, W3, b3, out, nEdges);
  } else {
    lp_main<false><<<1024, 256, 0, stream>>>(z, nullptr, ei, W1, b1, W2, b2, W3, b3, out, nEdges);
  }
}

// Round 5
// 189.111 us; speedup vs baseline: 2.4549x; 2.2013x over previous
//
#include <hip/hip_runtime.h>
#include <hip/hip_bf16.h>

typedef __attribute__((ext_vector_type(8))) short short8;
typedef __attribute__((ext_vector_type(4))) short short4v;
typedef __attribute__((ext_vector_type(4))) float f32x4;

__device__ __forceinline__ unsigned short f32_bf16(float f) {
  unsigned u = __float_as_uint(f);
  u += 0x7fffu + ((u >> 16) & 1u);  // round-to-nearest-even
  return (unsigned short)(u >> 16);
}

__device__ __forceinline__ short8 cvt8(float4 v0, float4 v1) {
  short8 f;
  f[0] = (short)f32_bf16(v0.x); f[1] = (short)f32_bf16(v0.y);
  f[2] = (short)f32_bf16(v0.z); f[3] = (short)f32_bf16(v0.w);
  f[4] = (short)f32_bf16(v1.x); f[5] = (short)f32_bf16(v1.y);
  f[6] = (short)f32_bf16(v1.z); f[7] = (short)f32_bf16(v1.w);
  return f;
}

// ---- pass 1: z (fp32) -> z_bf16 in workspace --------------------------------
__global__ __launch_bounds__(256) void cvt_bf16_kernel(const float* __restrict__ z,
                                                       unsigned short* __restrict__ zb,
                                                       int n) {
  int i = (blockIdx.x * 256 + threadIdx.x) * 8;
  if (i + 8 <= n) {
    float4 v0 = *(const float4*)(z + i);
    float4 v1 = *(const float4*)(z + i + 4);
    union { unsigned short us[8]; uint4 u4; } r;
    r.us[0] = f32_bf16(v0.x); r.us[1] = f32_bf16(v0.y);
    r.us[2] = f32_bf16(v0.z); r.us[3] = f32_bf16(v0.w);
    r.us[4] = f32_bf16(v1.x); r.us[5] = f32_bf16(v1.y);
    r.us[6] = f32_bf16(v1.z); r.us[7] = f32_bf16(v1.w);
    *(uint4*)(zb + i) = r.u4;
  }
}

// ---- pass 2: fused gather + 3-layer MLP + sigmoid ---------------------------
// 256-thread blocks (4 waves), __launch_bounds__(256,2): the gfx950 allocator
// splits the unified file ~50/50 arch/AGPR under a cap (measured: cap 128 ->
// 64 arch [R2/R3], cap 170 -> 84 arch [R4] -> spills). Cap 256 -> 128 arch,
// our ~95-105 arch need fits; occupancy then comes from ACTUAL usage
// (~130 total -> 3 waves/SIMD) instead of a forced cap.
// W1 + W2 fragments live in LDS (36 KB) to keep arch pressure low; per-wave
// h1 scratch 8 KB. LDS/block = 44 KB -> 3 blocks/CU -> 12 waves/CU target.
// A-frag: a[j]=A[m=lane&15][k=quad*8+j]; B-frag: b[j]=B[k=quad*8+j][n=lane&15]
// C/D:    D[row=quad*4+reg][col=lane&15]
// W1 fragments stored column-PERMUTED (ntile t, lane l15 -> col l15*4+t) so a
// lane's 4 layer-1 outputs are contiguous h1 cols -> one ds_write_b64.
// h1 swizzle: col' = (col + (row&7)*8) & 63  (keeps 4/8-element runs intact).
template <bool ZBF>
__global__ __launch_bounds__(256, 2) void lp_main(
    const float* __restrict__ zf, const unsigned short* __restrict__ zb,
    const int* __restrict__ ei,
    const float* __restrict__ W1, const float* __restrict__ b1,
    const float* __restrict__ W2, const float* __restrict__ b2,
    const float* __restrict__ W3, const float* __restrict__ b3,
    float* __restrict__ out, int nEdges) {
  __shared__ unsigned short w1l[32 * 64 * 8];               // 32 KB
  __shared__ unsigned short w2l[4 * 64 * 8];                // 4 KB
  __shared__ __align__(16) unsigned short h1s[4][16 * 64];  // 8 KB

  const int tid = threadIdx.x;
  const int wv  = tid >> 6;
  const int l   = tid & 63;
  const int l15 = l & 15;
  const int q   = l >> 4;

  // ---- stage W1 fragments into LDS (once per block, col-permuted) ----
#pragma unroll
  for (int pp = 0; pp < 8; ++pp) {
    int p = wv * 8 + pp;  // p = c*4 + t
    int c = p >> 2, t = p & 3;
    short8 f;
#pragma unroll
    for (int j = 0; j < 8; ++j)
      f[j] = (short)f32_bf16(W1[(c * 32 + q * 8 + j) * 64 + (l15 * 4 + t)]);
    *(short8*)(w1l + (p * 64 + l) * 8) = f;
  }
  // ---- stage W2 fragments into LDS (natural column order) ----
  {
    int p = tid >> 6;  // p = c*2 + t  (4 fragments, one per wave)
    int c = p >> 1, t = p & 1;
    short8 f;
#pragma unroll
    for (int j = 0; j < 8; ++j)
      f[j] = (short)f32_bf16(W2[(c * 32 + q * 8 + j) * 32 + (t * 16 + l15)]);
    *(short8*)(w2l + (p * 64 + l) * 8) = f;
  }

  float bb1[4];
#pragma unroll
  for (int t = 0; t < 4; ++t) bb1[t] = b1[l15 * 4 + t];  // permuted cols
  float bb2[2];
#pragma unroll
  for (int t = 0; t < 2; ++t) bb2[t] = b2[t * 16 + l15];
  const float w3a = W3[l15], w3b = W3[16 + l15], b3v = b3[0];

  __syncthreads();

  unsigned short* h1p = h1s[wv];

  const int nIter = (nEdges + 15) >> 4;
  const int stride = gridDim.x * 4;
  int iter = blockIdx.x * 4 + wv;

  // prefetch edge indices for first iteration
  int cS = 0, cD = 0;
  if (iter < nIter) {
    int e = iter * 16 + l15;
    e = e < nEdges ? e : nEdges - 1;
    cS = ei[e];
    cD = ei[nEdges + e];
  }

  for (; iter < nIter; iter += stride) {
    // ---- gather this tile's A fragments ----
    short8 a[8];
    if (ZBF) {
      const unsigned short* rs = zb + (size_t)cS * 128;
      const unsigned short* rd = zb + (size_t)cD * 128;
#pragma unroll
      for (int c = 0; c < 4; ++c) {
        int off = c * 32 + q * 8;
        a[c]     = *(const short8*)(rs + off);
        a[c + 4] = *(const short8*)(rd + off);
      }
    } else {
      const float* rs = zf + (size_t)cS * 128;
      const float* rd = zf + (size_t)cD * 128;
#pragma unroll
      for (int c = 0; c < 4; ++c) {
        int off = c * 32 + q * 8;
        a[c]     = cvt8(*(const float4*)(rs + off), *(const float4*)(rs + off + 4));
        a[c + 4] = cvt8(*(const float4*)(rd + off), *(const float4*)(rd + off + 4));
      }
    }

    // ---- prefetch edge indices for next iteration ----
    int nit = iter + stride;
    int nS = cS, nD = cD;
    if (nit < nIter) {
      int e = nit * 16 + l15;
      e = e < nEdges ? e : nEdges - 1;
      nS = ei[e];
      nD = ei[nEdges + e];
    }

    // ---- layer 1: [16,256] @ [256,64] + b1, W1 frags from LDS ----
    f32x4 acc[4];
#pragma unroll
    for (int t = 0; t < 4; ++t) {
      acc[t][0] = bb1[t]; acc[t][1] = bb1[t]; acc[t][2] = bb1[t]; acc[t][3] = bb1[t];
    }
#pragma unroll
    for (int c = 0; c < 8; ++c)
#pragma unroll
      for (int t = 0; t < 4; ++t) {
        short8 wf = *(const short8*)(w1l + ((c * 4 + t) * 64 + l) * 8);
        acc[t] = __builtin_amdgcn_mfma_f32_16x16x32_bf16(a[c], wf, acc[t], 0, 0, 0);
      }

    // ---- relu -> bf16 -> swizzled h1 (one ds_write_b64 per row) ----
#pragma unroll
    for (int r = 0; r < 4; ++r) {
      int m = q * 4 + r;
      int colb = (l15 * 4 + ((m & 7) << 3)) & 63;
      short4v v;
#pragma unroll
      for (int t = 0; t < 4; ++t) {
        float x = acc[t][r];
        x = x > 0.f ? x : 0.f;
        v[t] = (short)f32_bf16(x);
      }
      *(short4v*)(h1p + m * 64 + colb) = v;
    }

    // ---- layer 2: [16,64] @ [64,32] + b2 (per-wave LDS, no barrier) ----
    int rot = (l15 & 7) << 3;
    short8 a2_0 = *(const short8*)(h1p + l15 * 64 + ((q * 8 + rot) & 63));
    short8 a2_1 = *(const short8*)(h1p + l15 * 64 + ((q * 8 + 32 + rot) & 63));

    f32x4 acc2[2];
#pragma unroll
    for (int t = 0; t < 2; ++t) {
      acc2[t][0] = bb2[t]; acc2[t][1] = bb2[t]; acc2[t][2] = bb2[t]; acc2[t][3] = bb2[t];
    }
#pragma unroll
    for (int t = 0; t < 2; ++t) {
      short8 wf0 = *(const short8*)(w2l + ((0 * 2 + t) * 64 + l) * 8);
      acc2[t] = __builtin_amdgcn_mfma_f32_16x16x32_bf16(a2_0, wf0, acc2[t], 0, 0, 0);
      short8 wf1 = *(const short8*)(w2l + ((1 * 2 + t) * 64 + l) * 8);
      acc2[t] = __builtin_amdgcn_mfma_f32_16x16x32_bf16(a2_1, wf1, acc2[t], 0, 0, 0);
    }

    // ---- layer 3: per-lane partial, xor-reduce across 16 lanes ----
    float p[4];
#pragma unroll
    for (int r = 0; r < 4; ++r) {
      float h0 = acc2[0][r]; h0 = h0 > 0.f ? h0 : 0.f;
      float h1v = acc2[1][r]; h1v = h1v > 0.f ? h1v : 0.f;
      p[r] = h0 * w3a + h1v * w3b;
    }
#pragma unroll
    for (int m = 1; m < 16; m <<= 1)
#pragma unroll
      for (int r = 0; r < 4; ++r) p[r] += __shfl_xor(p[r], m, 64);

    if (l15 == 0) {
      int eb = iter * 16 + q * 4;
      float4 o;
      o.x = 1.f / (1.f + __expf(-(p[0] + b3v)));
      o.y = 1.f / (1.f + __expf(-(p[1] + b3v)));
      o.z = 1.f / (1.f + __expf(-(p[2] + b3v)));
      o.w = 1.f / (1.f + __expf(-(p[3] + b3v)));
      if (eb + 3 < nEdges) {
        *(float4*)(out + eb) = o;
      } else {
        if (eb < nEdges)     out[eb]     = o.x;
        if (eb + 1 < nEdges) out[eb + 1] = o.y;
        if (eb + 2 < nEdges) out[eb + 2] = o.z;
      }
    }

    cS = nS; cD = nD;
  }
}

extern "C" void kernel_launch(void* const* d_in, const int* in_sizes, int n_in,
                              void* d_out, int out_size, void* d_ws, size_t ws_size,
                              hipStream_t stream) {
  const float* z  = (const float*)d_in[0];
  const int* ei   = (const int*)d_in[1];
  const float* W1 = (const float*)d_in[2];
  const float* b1 = (const float*)d_in[3];
  const float* W2 = (const float*)d_in[4];
  const float* b2 = (const float*)d_in[5];
  const float* W3 = (const float*)d_in[6];
  const float* b3 = (const float*)d_in[7];
  float* out = (float*)d_out;

  const int nZ = in_sizes[0];
  const int nEdges = in_sizes[1] / 2;

  const bool useWs = ws_size >= (size_t)nZ * sizeof(unsigned short);
  if (useWs) {
    unsigned short* zb = (unsigned short*)d_ws;
    int nThr = nZ / 8;
    cvt_bf16_kernel<<<(nThr + 255) / 256, 256, 0, stream>>>(z, zb, nZ);
    lp_main<true><<<1024, 256, 0, stream>>>(z, zb, ei, W1, b1, W2, b2, W3, b3, out, nEdges);
  } else {
    lp_main<false><<<1024, 256, 0, stream>>>(z, nullptr, ei, W1, b1, W2, b2, W3, b3, out, nEdges);
  }
}